// Round 1
// baseline (979.330 us; speedup 1.0000x reference)
//
#include <hip/hip_runtime.h>
#include <cstdint>
#include <cstddef>

// Problem constants (from setup_inputs): B=10, Hi=Wi=64, C=64, M=8, Hb=Wb=128, U=64.
// instance_feature [B,Hi,Wi,C,M] f32 ; bg_feature [B,Hb,Wb,C] ; bbox [B,4,M] ;
// weights 3x3 convs HWIO ; object_n [B] int32. Output composed [B,Hb,Wb,C] f32.

#define CK1 16  // c-chunk for conv1 LDS staging

// ---------------------------------------------------------------------------
// conv1: 3x3 SAME conv, C=64 -> U=64, + bias + relu.
// One block = one output row segment of 64 px. 256 threads, each 4px x 4u.
// INST: input gathered from instance_feature [B,Hi,Wi,C,M] (fused transpose).
// ---------------------------------------------------------------------------
template<bool INST>
__global__ __launch_bounds__(256) void conv1_k(const float* __restrict__ src,
    const float* __restrict__ w, const float* __restrict__ bias,
    float* __restrict__ dst, int N, int H, int W)
{
  __shared__ float in_s[CK1][3][68];   // [c][ry][x+1], row stride 68 (16B aligned)
  __shared__ float w_s[9 * CK1][64];   // [(dy*3+dx)*CK1 + c][u]

  const int tid = threadIdx.x;
  const int tilesX = W >> 6;
  const int bid = blockIdx.x;
  const int xt = bid % tilesX;
  const int t2 = bid / tilesX;
  const int y = t2 % H;
  const int n = t2 / H;
  const int xb = xt << 6;

  const int u0 = (tid & 15) << 2;   // 4 consecutive output channels
  const int x0 = (tid >> 4) << 2;   // 4 consecutive output x (within tile)

  float acc[4][4];
  #pragma unroll
  for (int i = 0; i < 4; ++i) {
    acc[i][0] = 0.f; acc[i][1] = 0.f; acc[i][2] = 0.f; acc[i][3] = 0.f;
  }

  int b = 0, m = 0;
  if (INST) { b = n >> 3; m = n & 7; }

  for (int cc = 0; cc < 64 / CK1; ++cc) {
    const int c0 = cc * CK1;
    __syncthreads();  // protect LDS from previous chunk's readers
    // ---- stage input: rows y-1..y+1, x in [xb-1, xb+64], channels c0..c0+15
    for (int e = tid; e < CK1 * 3 * 66; e += 256) {
      int c = e & (CK1 - 1);
      int q = e >> 4;
      int xi = q % 66;
      int ry = q / 66;
      int gy = y + ry - 1;
      int gx = xb + xi - 1;
      float v = 0.f;
      if (gy >= 0 && gy < H && gx >= 0 && gx < W) {
        if (INST) {
          // instance_feature[b, gy, gx, c0+c, m]
          v = src[(size_t)b * 2097152 + (size_t)gy * 32768 + (size_t)gx * 512
                  + (size_t)(c0 + c) * 8 + m];
        } else {
          v = src[((size_t)(n * H + gy) * W + gx) * 64 + c0 + c];
        }
      }
      in_s[c][ry][xi] = v;
    }
    // ---- stage weights: w[dy][dx][c0+c][u]
    for (int e = tid; e < 9 * CK1 * 64; e += 256) {
      int u = e & 63;
      int q = e >> 6;          // k9*CK1 + c
      int c = q & (CK1 - 1);
      int k9 = q >> 4;
      w_s[q][u] = w[((size_t)k9 * 64 + c0 + c) * 64 + u];
    }
    __syncthreads();

    // ---- accumulate
    for (int c = 0; c < CK1; ++c) {
      #pragma unroll
      for (int dy = 0; dy < 3; ++dy) {
        const float* rowp = &in_s[c][dy][x0];
        float4 ra = *(const float4*)rowp;        // x0 .. x0+3  (16B aligned)
        float2 rb = *(const float2*)(rowp + 4);  // x0+4, x0+5
        float r[6] = {ra.x, ra.y, ra.z, ra.w, rb.x, rb.y};
        #pragma unroll
        for (int dx = 0; dx < 3; ++dx) {
          float4 wv = *(const float4*)&w_s[(dy * 3 + dx) * CK1 + c][u0];
          #pragma unroll
          for (int i = 0; i < 4; ++i) {
            float rv = r[i + dx];
            acc[i][0] += rv * wv.x;
            acc[i][1] += rv * wv.y;
            acc[i][2] += rv * wv.z;
            acc[i][3] += rv * wv.w;
          }
        }
      }
    }
  }

  float4 bv = *(const float4*)&bias[u0];
  #pragma unroll
  for (int i = 0; i < 4; ++i) {
    float4 o;
    o.x = fmaxf(acc[i][0] + bv.x, 0.f);
    o.y = fmaxf(acc[i][1] + bv.y, 0.f);
    o.z = fmaxf(acc[i][2] + bv.z, 0.f);
    o.w = fmaxf(acc[i][3] + bv.w, 0.f);
    *(float4*)&dst[((size_t)(n * H + y) * W + (xb + x0 + i)) * 64 + u0] = o;
  }
}

// ---------------------------------------------------------------------------
// conv2: 3x3 SAME conv, 64 -> 1 channel, + bias + relu.
// Block = 16x16 output tile, 1 thread per pixel, input staged via LDS in two
// 32-channel chunks. Row stride 24 -> exact 2-way bank aliasing (free);
// c-stride 433 -> conflict-free staging writes.
// ---------------------------------------------------------------------------
__global__ __launch_bounds__(256) void conv2_k(const float* __restrict__ hsrc,
    const float* __restrict__ w2, const float* __restrict__ b2,
    float* __restrict__ dst, int N, int H, int W)
{
  const int RS = 24;
  const int CS = 18 * 24 + 1;  // 433
  __shared__ float s[32 * (18 * 24 + 1)];
  __shared__ float wsm[576];

  const int tid = threadIdx.x;
  const int tilesX = W >> 4;
  const int bid = blockIdx.x;
  const int xt = bid % tilesX;
  const int q0 = bid / tilesX;
  const int yt = q0 % (H >> 4);
  const int n = q0 / (H >> 4);
  const int xb = xt << 4, yb = yt << 4;
  const int tx = tid & 15, ty = tid >> 4;

  for (int e = tid; e < 576; e += 256) wsm[e] = w2[e];

  float acc = 0.f;
  for (int cc = 0; cc < 2; ++cc) {
    const int c0 = cc << 5;
    if (cc) __syncthreads();
    for (int e = tid; e < 18 * 18 * 32; e += 256) {
      int c = e & 31;
      int p = e >> 5;
      int xx = p % 18;
      int yy = p / 18;
      int gy = yb + yy - 1, gx = xb + xx - 1;
      float v = 0.f;
      if (gy >= 0 && gy < H && gx >= 0 && gx < W)
        v = hsrc[((size_t)(n * H + gy) * W + gx) * 64 + c0 + c];
      s[c * CS + yy * RS + xx] = v;
    }
    __syncthreads();
    for (int c = 0; c < 32; ++c) {
      const float* sp = &s[c * CS + ty * RS + tx];
      const float* wp = &wsm[c0 + c];
      #pragma unroll
      for (int dy = 0; dy < 3; ++dy)
        #pragma unroll
        for (int dx = 0; dx < 3; ++dx)
          acc += sp[dy * RS + dx] * wp[(dy * 3 + dx) * 64];
    }
  }
  float bv = b2[0];
  dst[((size_t)n * H + yb + ty) * W + xb + tx] = fmaxf(acc + bv, 0.f);
}

// ---------------------------------------------------------------------------
// compose: per output pixel (b,h,w), per channel lane c:
//   denom = exp(bg_w) + sum_m e_m ; e_m = (in box & m<object_n & rw>0) exp(rw)
//   out = (exp(bg_w)*bg_c + sum_m e_m * bilinear(inst_feat_m, c)) / denom
// Fuses resize_and_pad (bilinear, half-pixel, floor-box semantics) for both
// the 1-channel weight map and the 64-channel features. 4 pixels per block.
// ---------------------------------------------------------------------------
__global__ __launch_bounds__(256) void compose_k(const float* __restrict__ IF,
    const float* __restrict__ bg, const float* __restrict__ bbox,
    const int* __restrict__ objn, const float* __restrict__ instw,
    const float* __restrict__ bgw, float* __restrict__ out)
{
  const int tid = threadIdx.x;
  const int c = tid & 63;
  const int pid = blockIdx.x * 4 + (tid >> 6);  // b*16384 + h*128 + w
  const int b = pid >> 14;
  const int rem = pid & 16383;
  const int hh = rem >> 7;
  const int www = rem & 127;

  const float ebg = expf(bgw[pid]);
  const float bgc = bg[(size_t)pid * 64 + c];
  float acc = ebg * bgc;
  float denom = ebg;
  const int nobj = objn[b];

  #pragma unroll
  for (int m = 0; m < 8; ++m) {
    if (m >= nobj) continue;
    const float y0b = bbox[b * 32 + m];
    const float y1b = bbox[b * 32 + 8 + m];
    const float x0b = bbox[b * 32 + 16 + m];
    const float x1b = bbox[b * 32 + 24 + m];
    const float ysz = floorf(128.f * (y1b - y0b));
    const float xsz = floorf(128.f * (x1b - x0b));
    const float yf = floorf(128.f * y0b);
    const float xf = floorf(128.f * x0b);
    const float ly = (float)hh - yf;
    const float lx = (float)www - xf;
    if (!(ly >= 0.f && ly < ysz && lx >= 0.f && lx < xsz)) continue;
    float sy = (ly + 0.5f) * 64.f / fmaxf(ysz, 1.f) - 0.5f;
    float sx = (lx + 0.5f) * 64.f / fmaxf(xsz, 1.f) - 0.5f;
    sy = fminf(fmaxf(sy, 0.f), 63.f);
    sx = fminf(fmaxf(sx, 0.f), 63.f);
    const int y0i = (int)floorf(sy);
    const int x0i = (int)floorf(sx);
    const int y1i = min(y0i + 1, 63);
    const int x1i = min(x0i + 1, 63);
    const float wy = sy - (float)y0i;
    const float wx = sx - (float)x0i;
    const float omwx = 1.f - wx, omwy = 1.f - wy;

    // bilinear of the conv'd weight map (same for all 64 lanes -> broadcast)
    const float* iw = instw + (size_t)(b * 8 + m) * 4096;
    const float v00 = iw[y0i * 64 + x0i];
    const float v01 = iw[y0i * 64 + x1i];
    const float v10 = iw[y1i * 64 + x0i];
    const float v11 = iw[y1i * 64 + x1i];
    const float rwv = (v00 * omwx + v01 * wx) * omwy + (v10 * omwx + v11 * wx) * wy;
    if (!(rwv > 0.f)) continue;   // rmask
    const float e = expf(rwv);
    denom += e;

    // bilinear of the raw instance feature, channel c
    const float* fb = IF + (size_t)b * 2097152 + (size_t)c * 8 + m;
    const float t00 = fb[(size_t)y0i * 32768 + (size_t)x0i * 512];
    const float t01 = fb[(size_t)y0i * 32768 + (size_t)x1i * 512];
    const float t10 = fb[(size_t)y1i * 32768 + (size_t)x0i * 512];
    const float t11 = fb[(size_t)y1i * 32768 + (size_t)x1i * 512];
    const float bil = (t00 * omwx + t01 * wx) * omwy + (t10 * omwx + t11 * wx) * wy;
    acc += e * bil;
  }
  out[(size_t)pid * 64 + c] = acc / denom;
}

// ---------------------------------------------------------------------------
extern "C" void kernel_launch(void* const* d_in, const int* in_sizes, int n_in,
                              void* d_out, int out_size, void* d_ws, size_t ws_size,
                              hipStream_t stream)
{
  const float* IF   = (const float*)d_in[0];   // [10,64,64,64,8]
  const float* BG   = (const float*)d_in[1];   // [10,128,128,64]
  const float* BBOX = (const float*)d_in[2];   // [10,4,8]
  // d_in[3] mrcnn_mask: unused by the reference forward
  const float* w1i = (const float*)d_in[4];
  const float* b1i = (const float*)d_in[5];
  const float* w2i = (const float*)d_in[6];
  const float* b2i = (const float*)d_in[7];
  const float* w1b = (const float*)d_in[8];
  const float* b1b = (const float*)d_in[9];
  const float* w2b = (const float*)d_in[10];
  const float* b2b = (const float*)d_in[11];
  const int* objn  = (const int*)d_in[12];
  float* out = (float*)d_out;

  float* ws    = (float*)d_ws;
  float* hbuf  = ws;                      // max(80*64*64*64, 10*128*128*64) = 20,971,520 f
  float* instw = ws + 20971520;           // 80*64*64 = 327,680 f
  float* bgwp  = instw + 327680;          // 10*128*128 = 163,840 f

  // instance branch: conv1 (fused transpose) -> conv2
  conv1_k<true><<<80 * 64, 256, 0, stream>>>(IF, w1i, b1i, hbuf, 80, 64, 64);
  conv2_k<<<80 * 4 * 4, 256, 0, stream>>>(hbuf, w2i, b2i, instw, 80, 64, 64);
  // bg branch (reuses hbuf; stream order serializes with conv2 above)
  conv1_k<false><<<10 * 128 * 2, 256, 0, stream>>>(BG, w1b, b1b, hbuf, 10, 128, 128);
  conv2_k<<<10 * 8 * 8, 256, 0, stream>>>(hbuf, w2b, b2b, bgwp, 10, 128, 128);
  // fused resize + softmax composition
  compose_k<<<163840 / 4, 256, 0, stream>>>(IF, BG, BBOX, objn, instw, bgwp, out);
}

// Round 4
// 824.742 us; speedup vs baseline: 1.1874x; 1.1874x over previous
//
#include <hip/hip_runtime.h>
#include <cstdint>
#include <cstddef>

// B=10, Hi=Wi=64, C=64, M=8, Hb=Wb=128, U=64.
// All-fp32 pipeline (bf16 conv fails: reference's rmask = (rw>0) flips at
// conv2 pre-activation zero-crossings; needs ~1e-6 accuracy -> fp32 VALU).
// conv1 v2: 3 output rows x 4 px x 4 u per thread -> FMA:LDS = 432:19 per ch.

// ---------------------------------------------------------------------------
// conv1_v2: 3x3 SAME conv, C=64 -> U=64, + bias + relu, fp32.
// Block = 256 threads (4 waves) -> output tile 3 rows x 64 px x 64 u.
// Thread: u0 = (tid&15)*4, x0 = (tid>>4)*4, 3 output rows.
// LDS per 8-ch chunk: input 5 rows x 66 px (stride 68), weights 9x8x64.
// INST: gathers from instance_feature [B,Hi,Wi,C,M] (fused transpose).
// ---------------------------------------------------------------------------
template<bool INST>
__global__ __launch_bounds__(256) void conv1_v2(const float* __restrict__ src,
    const float* __restrict__ w, const float* __restrict__ bias,
    float* __restrict__ dst, int N, int H, int W)
{
  __shared__ __align__(16) float in_s[5 * 8 * 68];   // [ir][c][xi], stride 68
  __shared__ __align__(16) float w_s[9 * 8 * 64];    // [k9][c][u]

  const int tid = threadIdx.x;
  const int tilesX = W >> 6;
  const int RG = (H + 2) / 3;
  const int bid = blockIdx.x;
  const int xt = bid % tilesX;
  const int t2 = bid / tilesX;
  const int rg = t2 % RG;
  const int n = t2 / RG;
  const int yb = rg * 3;
  const int xb = xt << 6;

  const int u0 = (tid & 15) << 2;
  const int x0 = (tid >> 4) << 2;

  float acc[3][4][4];
  #pragma unroll
  for (int yo = 0; yo < 3; ++yo)
    #pragma unroll
    for (int i = 0; i < 4; ++i)
      #pragma unroll
      for (int j = 0; j < 4; ++j)
        acc[yo][i][j] = 0.f;

  int b = 0, m = 0;
  if (INST) { b = n >> 3; m = n & 7; }

  for (int cc = 0; cc < 8; ++cc) {
    const int c0 = cc * 8;
    __syncthreads();  // protect LDS from previous chunk's readers
    // ---- stage input: rows yb-1..yb+3, x in [xb-1, xb+64], channels c0..c0+7
    for (int e = tid; e < 2640; e += 256) {
      int cl = e & 7;
      int q = e >> 3;
      int xi = q % 66;
      int ir = q / 66;
      int gy = yb + ir - 1;
      int gx = xb + xi - 1;
      float v = 0.f;
      if (gy >= 0 && gy < H && gx >= 0 && gx < W) {
        if (INST) {
          v = src[(size_t)b * 2097152 + (size_t)gy * 32768 + (size_t)gx * 512
                  + (size_t)(c0 + cl) * 8 + m];
        } else {
          v = src[((size_t)(n * H + gy) * W + gx) * 64 + c0 + cl];
        }
      }
      in_s[(ir * 8 + cl) * 68 + xi] = v;
    }
    // ---- stage weights: w[k9][c0+c][u]
    for (int e = tid; e < 4608; e += 256) {
      int u = e & 63;
      int q = e >> 6;       // k9*8 + c
      int c = q & 7;
      int k9 = q >> 3;
      w_s[q * 64 + u] = w[((size_t)k9 * 64 + c0 + c) * 64 + u];
    }
    __syncthreads();

    // ---- accumulate: per channel, 9 w-vectors in regs, 5 input rows
    for (int c = 0; c < 8; ++c) {
      float4 wr[9];
      #pragma unroll
      for (int t = 0; t < 9; ++t)
        wr[t] = *(const float4*)&w_s[(t * 8 + c) * 64 + u0];
      #pragma unroll
      for (int ir = 0; ir < 5; ++ir) {
        const float* rp = &in_s[(ir * 8 + c) * 68 + x0];
        float4 ra = *(const float4*)rp;        // 16B-aligned (68 % 4 == 0)
        float2 rb = *(const float2*)(rp + 4);
        float r[6] = {ra.x, ra.y, ra.z, ra.w, rb.x, rb.y};
        #pragma unroll
        for (int dy = 0; dy < 3; ++dy) {
          const int yo = ir - dy;
          if (yo < 0 || yo > 2) continue;      // folds at compile time
          #pragma unroll
          for (int dx = 0; dx < 3; ++dx) {
            float4 wv = wr[dy * 3 + dx];
            #pragma unroll
            for (int i = 0; i < 4; ++i) {
              float rv = r[i + dx];
              acc[yo][i][0] += rv * wv.x;
              acc[yo][i][1] += rv * wv.y;
              acc[yo][i][2] += rv * wv.z;
              acc[yo][i][3] += rv * wv.w;
            }
          }
        }
      }
    }
  }

  float4 bv = *(const float4*)&bias[u0];
  #pragma unroll
  for (int yo = 0; yo < 3; ++yo) {
    const int gy = yb + yo;
    if (gy < H) {
      #pragma unroll
      for (int i = 0; i < 4; ++i) {
        float4 o;
        o.x = fmaxf(acc[yo][i][0] + bv.x, 0.f);
        o.y = fmaxf(acc[yo][i][1] + bv.y, 0.f);
        o.z = fmaxf(acc[yo][i][2] + bv.z, 0.f);
        o.w = fmaxf(acc[yo][i][3] + bv.w, 0.f);
        *(float4*)&dst[((size_t)(n * H + gy) * W + (xb + x0 + i)) * 64 + u0] = o;
      }
    }
  }
}

// ---------------------------------------------------------------------------
// conv2: 3x3 SAME conv, 64 -> 1 ch, + bias + relu, fp32 (round-1 proven).
// ---------------------------------------------------------------------------
__global__ __launch_bounds__(256) void conv2_k(const float* __restrict__ hsrc,
    const float* __restrict__ w2, const float* __restrict__ b2,
    float* __restrict__ dst, int N, int H, int W)
{
  const int RS = 24;
  const int CS = 18 * 24 + 1;  // 433
  __shared__ float s[32 * (18 * 24 + 1)];
  __shared__ float wsm[576];

  const int tid = threadIdx.x;
  const int tilesX = W >> 4;
  const int bid = blockIdx.x;
  const int xt = bid % tilesX;
  const int q0 = bid / tilesX;
  const int yt = q0 % (H >> 4);
  const int n = q0 / (H >> 4);
  const int xb = xt << 4, yb = yt << 4;
  const int tx = tid & 15, ty = tid >> 4;

  for (int e = tid; e < 576; e += 256) wsm[e] = w2[e];

  float acc = 0.f;
  for (int cc = 0; cc < 2; ++cc) {
    const int c0 = cc << 5;
    if (cc) __syncthreads();
    for (int e = tid; e < 18 * 18 * 32; e += 256) {
      int c = e & 31;
      int p = e >> 5;
      int xx = p % 18;
      int yy = p / 18;
      int gy = yb + yy - 1, gx = xb + xx - 1;
      float v = 0.f;
      if (gy >= 0 && gy < H && gx >= 0 && gx < W)
        v = hsrc[((size_t)(n * H + gy) * W + gx) * 64 + c0 + c];
      s[c * CS + yy * RS + xx] = v;
    }
    __syncthreads();
    for (int c = 0; c < 32; ++c) {
      const float* sp = &s[c * CS + ty * RS + tx];
      const float* wp = &wsm[c0 + c];
      #pragma unroll
      for (int dy = 0; dy < 3; ++dy)
        #pragma unroll
        for (int dx = 0; dx < 3; ++dx)
          acc += sp[dy * RS + dx] * wp[(dy * 3 + dx) * 64];
    }
  }
  float bv = b2[0];
  dst[((size_t)n * H + yb + ty) * W + xb + tx] = fmaxf(acc + bv, 0.f);
}

// ---------------------------------------------------------------------------
// compose: fused resize_and_pad + masked-exp softmax composition (proven).
// ---------------------------------------------------------------------------
__global__ __launch_bounds__(256) void compose_k(const float* __restrict__ IF,
    const float* __restrict__ bg, const float* __restrict__ bbox,
    const int* __restrict__ objn, const float* __restrict__ instw,
    const float* __restrict__ bgw, float* __restrict__ out)
{
  const int tid = threadIdx.x;
  const int c = tid & 63;
  const int pid = blockIdx.x * 4 + (tid >> 6);  // b*16384 + h*128 + w
  const int b = pid >> 14;
  const int rem = pid & 16383;
  const int hh = rem >> 7;
  const int www = rem & 127;

  const float ebg = expf(bgw[pid]);
  const float bgc = bg[(size_t)pid * 64 + c];
  float acc = ebg * bgc;
  float denom = ebg;
  const int nobj = objn[b];

  #pragma unroll
  for (int m = 0; m < 8; ++m) {
    if (m >= nobj) continue;
    const float y0b = bbox[b * 32 + m];
    const float y1b = bbox[b * 32 + 8 + m];
    const float x0b = bbox[b * 32 + 16 + m];
    const float x1b = bbox[b * 32 + 24 + m];
    const float ysz = floorf(128.f * (y1b - y0b));
    const float xsz = floorf(128.f * (x1b - x0b));
    const float yf = floorf(128.f * y0b);
    const float xf = floorf(128.f * x0b);
    const float ly = (float)hh - yf;
    const float lx = (float)www - xf;
    if (!(ly >= 0.f && ly < ysz && lx >= 0.f && lx < xsz)) continue;
    float sy = (ly + 0.5f) * 64.f / fmaxf(ysz, 1.f) - 0.5f;
    float sx = (lx + 0.5f) * 64.f / fmaxf(xsz, 1.f) - 0.5f;
    sy = fminf(fmaxf(sy, 0.f), 63.f);
    sx = fminf(fmaxf(sx, 0.f), 63.f);
    const int y0i = (int)floorf(sy);
    const int x0i = (int)floorf(sx);
    const int y1i = min(y0i + 1, 63);
    const int x1i = min(x0i + 1, 63);
    const float wy = sy - (float)y0i;
    const float wx = sx - (float)x0i;
    const float omwx = 1.f - wx, omwy = 1.f - wy;

    const float* iw = instw + (size_t)(b * 8 + m) * 4096;
    const float v00 = iw[y0i * 64 + x0i];
    const float v01 = iw[y0i * 64 + x1i];
    const float v10 = iw[y1i * 64 + x0i];
    const float v11 = iw[y1i * 64 + x1i];
    const float rwv = (v00 * omwx + v01 * wx) * omwy + (v10 * omwx + v11 * wx) * wy;
    if (!(rwv > 0.f)) continue;   // rmask
    const float e = expf(rwv);
    denom += e;

    const float* fb = IF + (size_t)b * 2097152 + (size_t)c * 8 + m;
    const float t00 = fb[(size_t)y0i * 32768 + (size_t)x0i * 512];
    const float t01 = fb[(size_t)y0i * 32768 + (size_t)x1i * 512];
    const float t10 = fb[(size_t)y1i * 32768 + (size_t)x0i * 512];
    const float t11 = fb[(size_t)y1i * 32768 + (size_t)x1i * 512];
    const float bil = (t00 * omwx + t01 * wx) * omwy + (t10 * omwx + t11 * wx) * wy;
    acc += e * bil;
  }
  out[(size_t)pid * 64 + c] = acc / denom;
}

// ---------------------------------------------------------------------------
extern "C" void kernel_launch(void* const* d_in, const int* in_sizes, int n_in,
                              void* d_out, int out_size, void* d_ws, size_t ws_size,
                              hipStream_t stream)
{
  const float* IF   = (const float*)d_in[0];   // [10,64,64,64,8]
  const float* BG   = (const float*)d_in[1];   // [10,128,128,64]
  const float* BBOX = (const float*)d_in[2];   // [10,4,8]
  // d_in[3] mrcnn_mask: unused by the reference forward
  const float* w1i = (const float*)d_in[4];
  const float* b1i = (const float*)d_in[5];
  const float* w2i = (const float*)d_in[6];
  const float* b2i = (const float*)d_in[7];
  const float* w1b = (const float*)d_in[8];
  const float* b1b = (const float*)d_in[9];
  const float* w2b = (const float*)d_in[10];
  const float* b2b = (const float*)d_in[11];
  const int* objn  = (const int*)d_in[12];
  float* out = (float*)d_out;

  float* ws    = (float*)d_ws;
  float* hbuf  = ws;                      // max(80*64*64*64, 10*128*128*64) = 20,971,520 f
  float* instw = ws + 20971520;           // 80*64*64 = 327,680 f
  float* bgwp  = instw + 327680;          // 10*128*128 = 163,840 f

  // instance branch: conv1 (fused transpose) -> conv2
  conv1_v2<true><<<80 * 22, 256, 0, stream>>>(IF, w1i, b1i, hbuf, 80, 64, 64);
  conv2_k<<<80 * 4 * 4, 256, 0, stream>>>(hbuf, w2i, b2i, instw, 80, 64, 64);
  // bg branch (reuses hbuf; stream order serializes with conv2 above)
  conv1_v2<false><<<10 * 43 * 2, 256, 0, stream>>>(BG, w1b, b1b, hbuf, 10, 128, 128);
  conv2_k<<<10 * 8 * 8, 256, 0, stream>>>(hbuf, w2b, b2b, bgwp, 10, 128, 128);
  // fused resize + softmax composition
  compose_k<<<163840 / 4, 256, 0, stream>>>(IF, BG, BBOX, objn, instw, bgwp, out);
}